// Round 1
// 387.300 us; speedup vs baseline: 1.0202x; 1.0202x over previous
//
#include <hip/hip_runtime.h>

#define N_NODES 100000
#define N_EDGES 800000
#define N_IN    256
#define N_H     128
#define M_TOT   (2 * N_NODES)

typedef __bf16 bfx8 __attribute__((ext_vector_type(8)));
typedef unsigned short u16x8 __attribute__((ext_vector_type(8)));
typedef float fx4 __attribute__((ext_vector_type(4)));

__device__ inline unsigned short f2bf(float f) {
    union { float f; unsigned u; } v; v.f = f;
    return (unsigned short)((v.u + 0x7FFF + ((v.u >> 16) & 1)) >> 16);  // RNE
}
__device__ inline float bf2f(unsigned short s) {
    union { unsigned u; float f; } v; v.u = ((unsigned)s) << 16;
    return v.f;
}

__device__ inline void async16(const void* g, void* l) {
    __builtin_amdgcn_global_load_lds((const __attribute__((address_space(1))) void*)g,
                                     (__attribute__((address_space(3))) void*)l, 16, 0, 0);
}

// ------------- fused persistent B-stationary GEMM + edge scatter -------------
// Blocks [0, NSB2): scatter edges into CSR slots (dispatched first, churn fast
//   while persistent GEMM blocks fill in behind them).
// Blocks [NSB2, NSB2+NGB2): persistent GEMM. 256 thr = 4 waves; wave w owns
//   output cols [w*32, w*32+32) with W^T held in 64 VGPRs (loaded once).
//   x rows staged fp32 via global_load_lds, double-buffered 32 KB LDS,
//   counted vmcnt(4) so next-tile DMA stays in flight across barriers.
//   LDS 16-way read conflict killed by XOR swizzle on BOTH sides (src + read).
#define NT    12500   // 16-row tiles (200000/16); 6250 per branch, no straddle
#define NTB1  6250
#define NSB2  3125    // 800000/256
#define NGB2  1024    // 4 blocks/CU x 256 CU resident

__global__ __launch_bounds__(256, 4) void gemm_scatter_kernel(
        const float* __restrict__ x1, const float* __restrict__ x2,
        const unsigned short* __restrict__ wT,     // [N_H][N_IN] bf16 bits
        unsigned short* __restrict__ hb,           // [N_NODES][2][N_H] bf16 bits
        const int* __restrict__ ei, const float* __restrict__ ew,
        int* __restrict__ cursor, int2* __restrict__ edata) {
    const int t = threadIdx.x;
    if (blockIdx.x < NSB2) {                       // ---- scatter part ----
        int e = blockIdx.x * 256 + t;              // 3125*256 == 800000 exactly
        int row = ei[e];
        int pos = atomicAdd(cursor + row, 1);
        edata[pos] = make_int2(ei[N_EDGES + e] << 8, __float_as_int(ew[e]));
        return;
    }
    // ---- persistent GEMM part ----
    __shared__ __align__(16) float Abuf[2][16][256];   // 32 KB, double buffer
    const int wv = t >> 6, ln = t & 63;
    const int quad = ln >> 4, l16 = ln & 15, sw = l16 & 7;

    // stage tile TT (16 rows x 256 fp32) into Abuf[buf]; wave wv does 4 rows.
    // source is XOR-permuted within each 128B line so that physical LDS slot p
    // of row r holds logical slot p^(r&7)  (reader applies the same XOR).
#define STAGE(buf, TT) do {                                                    \
        int br_ = (TT) >= NTB1;                                                \
        const float* xs_ = br_ ? x2 : x1;                                      \
        const float* base_ = xs_ + (size_t)((TT) - br_ * NTB1) * (16 * N_IN);  \
        _Pragma("unroll")                                                      \
        for (int i_ = 0; i_ < 4; ++i_) {                                       \
            int r_ = wv * 4 + i_;                                              \
            async16(base_ + (size_t)r_ * N_IN + ((ln ^ (r_ & 7)) << 2),        \
                    &Abuf[(buf)][r_][0]);                                      \
        }                                                                      \
    } while (0)

    int T = blockIdx.x - NSB2;                     // 0..NGB2-1, then += NGB2
    STAGE(0, T);

    // B-stationary: wave's 32 cols x 256 k of W^T in registers (16 frags).
    bfx8 Bf[2][8];
#pragma unroll
    for (int c2 = 0; c2 < 2; ++c2)
#pragma unroll
        for (int kc = 0; kc < 8; ++kc)
            Bf[c2][kc] = *(const bfx8*)(wT +
                (size_t)(wv * 32 + c2 * 16 + l16) * N_IN + kc * 32 + quad * 8);

    int cur = 0;
    for (; T < NT; T += NGB2) {
        int Tn = T + NGB2;
        if (Tn < NT) {
            STAGE(cur ^ 1, Tn);                    // 4 DMAs stay in flight
            asm volatile("s_waitcnt vmcnt(4)" ::: "memory");   // cur + stores done
        } else {
            asm volatile("s_waitcnt vmcnt(0)" ::: "memory");   // tail drain
        }
        asm volatile("s_barrier" ::: "memory");    // all waves' cur DMAs landed
        {
            int br = T >= NTB1;
            int node0 = (T - br * NTB1) * 16;
            fx4 acc0 = {0.f, 0.f, 0.f, 0.f}, acc1 = {0.f, 0.f, 0.f, 0.f};
            const float* rowp = &Abuf[cur][l16][0];
#pragma unroll
            for (int kc = 0; kc < 8; ++kc) {
                int s0 = kc * 8 + quad * 2;
                fx4 lo = *(const fx4*)(rowp + (((s0    ) ^ sw) << 2));
                fx4 hi = *(const fx4*)(rowp + (((s0 + 1) ^ sw) << 2));
                u16x8 au;
                au[0] = f2bf(lo[0]); au[1] = f2bf(lo[1]);
                au[2] = f2bf(lo[2]); au[3] = f2bf(lo[3]);
                au[4] = f2bf(hi[0]); au[5] = f2bf(hi[1]);
                au[6] = f2bf(hi[2]); au[7] = f2bf(hi[3]);
                bfx8 af = __builtin_bit_cast(bfx8, au);
                acc0 = __builtin_amdgcn_mfma_f32_16x16x32_bf16(af, Bf[0][kc], acc0, 0, 0, 0);
                acc1 = __builtin_amdgcn_mfma_f32_16x16x32_bf16(af, Bf[1][kc], acc1, 0, 0, 0);
            }
            // C/D: out-row = quad*4 + r, col = c2*16 + l16 (verified mapping)
            unsigned short* hp = hb + (size_t)node0 * 256 + br * 128 + wv * 32 + l16;
#pragma unroll
            for (int r = 0; r < 4; ++r) {
                size_t off = (size_t)(quad * 4 + r) * 256;
                hp[off]      = f2bf(acc0[r]);
                hp[off + 16] = f2bf(acc1[r]);
            }
        }
        asm volatile("s_barrier" ::: "memory");    // done reading cur
        cur ^= 1;
    }
#undef STAGE
}

// ------- prep: histogram (blocks 0..3124) + W^T bf16 (32 blks) + wsum (1) ----
#define HIST_BLKS 3125   // ceil(800000/256)
__global__ __launch_bounds__(256) void prep_kernel(const int* __restrict__ ei,
                                                   int* __restrict__ deg,
                                                   const float* __restrict__ W,
                                                   unsigned short* __restrict__ wT,
                                                   const float* __restrict__ linW,
                                                   const float* __restrict__ linb,
                                                   float* __restrict__ wsum) {
    const int t = threadIdx.x;
    if (blockIdx.x < HIST_BLKS) {
        int e = blockIdx.x * 256 + t;
        if (e < N_EDGES) atomicAdd(deg + ei[e], 1);
    } else if (blockIdx.x < HIST_BLKS + 32) {
        int kb = (blockIdx.x - HIST_BLKS) * 8;     // 8 k-rows per block
#pragma unroll
        for (int p = 0; p < 4; ++p) {
            int idx = p * 256 + t;                 // 0..1023
            int k = kb + (idx >> 7), n = idx & 127;
            wT[(size_t)n * N_IN + k] = f2bf(W[(size_t)k * N_H + n]);  // coalesced read
        }
    } else {
        int j = t;
        if (j < N_H) {
            float s = 0.f;
            for (int o = 0; o < N_H; ++o) s += linW[j * N_H + o];
            wsum[j] = s;
        }
        if (j == N_H) {
            float s = 0.f;
            for (int o = 0; o < N_H; ++o) s += linb[o];
            wsum[N_H] = s;
        }
    }
}

// ---------------- scans ------------------------------------------------------
__global__ __launch_bounds__(256) void scan1_kernel(const int* __restrict__ deg,
                                                    int* __restrict__ part,
                                                    int* __restrict__ bsum) {
    __shared__ int s[256];
    int g = blockIdx.x * 256 + threadIdx.x;
    int v = (g < N_NODES) ? deg[g] : 0;
    s[threadIdx.x] = v;
    __syncthreads();
#pragma unroll
    for (int off = 1; off < 256; off <<= 1) {
        int t = (threadIdx.x >= off) ? s[threadIdx.x - off] : 0;
        __syncthreads();
        s[threadIdx.x] += t;
        __syncthreads();
    }
    if (g < N_NODES) part[g] = s[threadIdx.x] - v;
    if (threadIdx.x == 255) bsum[blockIdx.x] = s[255];
}

#define NBLK_SCAN 391
__global__ void scan2_kernel(int* __restrict__ bsum) {
    __shared__ int s[512];
    int v = (threadIdx.x < NBLK_SCAN) ? bsum[threadIdx.x] : 0;
    s[threadIdx.x] = v;
    __syncthreads();
#pragma unroll
    for (int off = 1; off < 512; off <<= 1) {
        int t = (threadIdx.x >= off) ? s[threadIdx.x - off] : 0;
        __syncthreads();
        s[threadIdx.x] += t;
        __syncthreads();
    }
    if (threadIdx.x < NBLK_SCAN) bsum[threadIdx.x] = s[threadIdx.x] - v;
}

__global__ __launch_bounds__(256) void scan3_kernel(const int* __restrict__ part,
                                                    const int* __restrict__ bsum,
                                                    int* __restrict__ off,
                                                    int* __restrict__ cursor) {
    int g = blockIdx.x * 256 + threadIdx.x;
    if (g < N_NODES) {
        int o = part[g] + bsum[blockIdx.x];
        off[g] = o;
        cursor[g] = o;
    }
    if (g == 0) off[N_NODES] = N_EDGES;
}

// ------- fused segment-sum SPMM + bias + PReLU + wsum-dot, BOTH branches -----
// hb is now [node][h1(128)|h2(128)] interleaved: one edge's gather touches a
// single 512B region (4 consecutive 128B lines) instead of two far-apart rows.
__global__ __launch_bounds__(256) void gcn_seg_kernel(const int* __restrict__ off,
                                                      const int2* __restrict__ edata,
                                                      const unsigned short* __restrict__ hb,
                                                      const float* __restrict__ gcn_bias,
                                                      const float* __restrict__ prelu_a,
                                                      const float* __restrict__ wsum,
                                                      float* __restrict__ zout) {
    const int wave = threadIdx.x >> 6, lane = threadIdx.x & 63;
    const int node = blockIdx.x * 4 + wave;        // 0..99999 (grid 25000)
    const int s = __builtin_amdgcn_readfirstlane(off[node]);
    const int e = __builtin_amdgcn_readfirstlane(off[node + 1]);
    const int l2 = lane * 2;
    float a0 = 0.f, a1 = 0.f;                      // branch 1 accum
    float b0 = 0.f, b1 = 0.f;                      // branch 2 accum
    int i = s;
    for (; i + 1 < e; i += 2) {
        int2 E0 = edata[i], E1 = edata[i + 1];     // E.x = col*256
        float w0 = __int_as_float(E0.y), w1 = __int_as_float(E1.y);
        ushort2 p10 = *(const ushort2*)(hb + E0.x + l2);
        ushort2 p20 = *(const ushort2*)(hb + E0.x + 128 + l2);
        ushort2 p11 = *(const ushort2*)(hb + E1.x + l2);
        ushort2 p21 = *(const ushort2*)(hb + E1.x + 128 + l2);
        a0 += w0 * bf2f(p10.x) + w1 * bf2f(p11.x);
        a1 += w0 * bf2f(p10.y) + w1 * bf2f(p11.y);
        b0 += w0 * bf2f(p20.x) + w1 * bf2f(p21.x);
        b1 += w0 * bf2f(p20.y) + w1 * bf2f(p21.y);
    }
    if (i < e) {
        int2 E0 = edata[i];
        float w0 = __int_as_float(E0.y);
        ushort2 p10 = *(const ushort2*)(hb + E0.x + l2);
        ushort2 p20 = *(const ushort2*)(hb + E0.x + 128 + l2);
        a0 += w0 * bf2f(p10.x);
        a1 += w0 * bf2f(p10.y);
        b0 += w0 * bf2f(p20.x);
        b1 += w0 * bf2f(p20.y);
    }
    const float alpha = prelu_a[0];
    const float g0 = gcn_bias[l2], g1 = gcn_bias[l2 + 1];
    const float q0 = wsum[l2],     q1 = wsum[l2 + 1];
    float v0 = a0 + g0, v1 = a1 + g1;
    float u0 = b0 + g0, u1 = b1 + g1;
    v0 = (v0 >= 0.f) ? v0 : alpha * v0;
    v1 = (v1 >= 0.f) ? v1 : alpha * v1;
    u0 = (u0 >= 0.f) ? u0 : alpha * u0;
    u1 = (u1 >= 0.f) ? u1 : alpha * u1;
    float s1 = v0 * q0 + v1 * q1;
    float s2 = u0 * q0 + u1 * q1;
#pragma unroll
    for (int o = 32; o; o >>= 1) {
        s1 += __shfl_down(s1, o, 64);
        s2 += __shfl_down(s2, o, 64);
    }
    if (lane == 0) {
        zout[node]           = s1 + wsum[128];     // wsum[128] = b_sum
        zout[node + N_NODES] = s2 + wsum[128];
    }
}

extern "C" void kernel_launch(void* const* d_in, const int* in_sizes, int n_in,
                              void* d_out, int out_size, void* d_ws, size_t ws_size,
                              hipStream_t stream) {
    const float* x1 = (const float*)d_in[0];
    const float* x2 = (const float*)d_in[1];
    const int*   ei = (const int*)d_in[2];
    const float* ew = (const float*)d_in[3];
    const float* Wg = (const float*)d_in[4];
    const float* gb = (const float*)d_in[5];
    const float* pa = (const float*)d_in[6];
    const float* lW = (const float*)d_in[7];
    const float* lb = (const float*)d_in[8];
    float* zout = (float*)d_out;

    unsigned short* hb   = (unsigned short*)d_ws;               // 25.6M u16
    int2*  edata  = (int2*)(hb + (size_t)M_TOT * N_H);          // 800k int2
    unsigned short* wT   = (unsigned short*)(edata + N_EDGES);  // 32768 u16
    int*   deg    = (int*)(wT + N_IN * N_H);                    // 100096 i
    int*   part   = deg + 100096;
    int*   off    = part + 100096;                              // uses 100001
    int*   cursor = off + 100096;
    int*   bsum   = cursor + 100096;                            // 512 i
    float* wsum   = (float*)(bsum + 512);                       // 129 f

    hipMemsetAsync(deg, 0, (size_t)N_NODES * sizeof(int), stream);
    prep_kernel<<<HIST_BLKS + 33, 256, 0, stream>>>(ei, deg, Wg, wT, lW, lb, wsum);
    scan1_kernel<<<NBLK_SCAN, 256, 0, stream>>>(deg, part, bsum);
    scan2_kernel<<<1, 512, 0, stream>>>(bsum);
    scan3_kernel<<<NBLK_SCAN, 256, 0, stream>>>(part, bsum, off, cursor);
    gemm_scatter_kernel<<<NSB2 + NGB2, 256, 0, stream>>>(x1, x2, wT, hb,
                                                         ei, ew, cursor, edata);
    gcn_seg_kernel<<<N_NODES / 4, 256, 0, stream>>>(off, edata, hb, gb, pa, wsum, zout);
}